// Round 3
// baseline (479.902 us; speedup 1.0000x reference)
//
#include <hip/hip_runtime.h>

#define TAGS 64
#define SOS_IDX 1
#define EOS_IDX 2

typedef __attribute__((ext_vector_type(2))) float f2;

// Broadcast lane l's value (uniform l) -> SGPR. Used ONCE per step (mask only).
__device__ __forceinline__ float rl(float v, int l) {
    return __int_as_float(__builtin_amdgcn_readlane(__float_as_int(v), l));
}

// One wave per batch element; lane i owns tag i.
// u[i] = exp(score[i] - L); step: u' = exp(h_t) * (E u) / z, Lsum += log2(z), z = u_prev[3].
// u all-to-all via LDS broadcast reads (ds_read_b128, VGPR operands -> no SGPR hazards).
__global__ __launch_bounds__(64, 1) void crf_fwd_kernel(
    const float* __restrict__ h,
    const float* __restrict__ mask,
    const float* __restrict__ trans,
    float* __restrict__ out,
    int S)
{
    const int b = blockIdx.x;
    const int lane = threadIdx.x;

    __shared__ float u_sh[TAGS];

    // E row for this lane, packed into float2 pairs: ew2[k] = exp(trans[lane][2k,2k+1])
    f2 ew2[32];
    {
        const float4* t4 = reinterpret_cast<const float4*>(trans);
        #pragma unroll
        for (int k = 0; k < 16; ++k) {
            float4 v = t4[lane * 16 + k];
            f2 lo, hi;
            lo.x = __expf(v.x); lo.y = __expf(v.y);   // exp(-10000) -> 0 exact
            hi.x = __expf(v.z); hi.y = __expf(v.w);
            ew2[2*k]   = lo;
            ew2[2*k+1] = hi;
        }
    }

    const float* hb = h + (size_t)b * (size_t)S * TAGS + lane;
    const float* mb = mask + (size_t)b * (size_t)S;

    float u  = (lane == SOS_IDX) ? 1.0f : 0.0f;  // exp(score0), score0[SOS]=0
    float Ls = 0.0f;                              // sum of log2(z)

    // h prefetch, depth 8 (coalesced 256B/wave/step)
    float hbuf[8];
    #pragma unroll
    for (int q = 0; q < 8; ++q) {
        int t = (q < S) ? q : (S - 1);
        hbuf[q] = hb[(size_t)t * TAGS];
    }

    // mask: one coalesced load per 64-step chunk (prefetched a chunk ahead);
    // per-step scalar via a single readlane. Assumes S % 64 == 0 (S=1024).
    const int NC = S >> 6;
    float mreg = mb[lane];

    const float4* u4 = reinterpret_cast<const float4*>(u_sh);

    for (int c = 0; c < NC; ++c) {
        const int cn = (c + 1 < NC) ? (c + 1) : c;
        float mreg_next = mb[(size_t)cn * 64 + lane];   // used 64 steps from now

        for (int t0 = 0; t0 < 64; t0 += 8) {
            // exp(h) for this 8-step group (loads issued 8 steps ago)
            float ehq[8];
            #pragma unroll
            for (int q = 0; q < 8; ++q) ehq[q] = __expf(hbuf[q]);
            // issue next group's h loads
            const int base = c * 64 + t0 + 8;
            #pragma unroll
            for (int q = 0; q < 8; ++q) {
                int tn = base + q;
                if (tn > S - 1) tn = S - 1;
                hbuf[q] = hb[(size_t)tn * TAGS];
            }

            #pragma unroll
            for (int q = 0; q < 8; ++q) {
                const float m = rl(mreg, t0 + q);   // uniform; only SGPR use/step

                u_sh[lane] = u;
                __builtin_amdgcn_wave_barrier();    // single wave: LDS in-order;
                                                    // fence compiler reordering
                // broadcast-read all 64 u's (same-address b128: conflict-free)
                float4 cc[16];
                #pragma unroll
                for (int k = 0; k < 16; ++k) cc[k] = u4[k];

                float z = cc[0].w;                  // u_prev[3]; finite after t=0
                z = (z > 0.0f) ? z : 1.0f;          // only step 0 has u[3]==0
                const float r = __builtin_amdgcn_rcpf(z);

                f2 acc[8];
                #pragma unroll
                for (int i = 0; i < 8; ++i) { acc[i].x = 0.f; acc[i].y = 0.f; }
                #pragma unroll
                for (int k = 0; k < 16; ++k) {
                    f2 lo, hi;
                    lo.x = cc[k].x; lo.y = cc[k].y;
                    hi.x = cc[k].z; hi.y = cc[k].w;
                    acc[(2*k)   & 7] = __builtin_elementwise_fma(ew2[2*k],   lo, acc[(2*k)   & 7]);
                    acc[(2*k+1) & 7] = __builtin_elementwise_fma(ew2[2*k+1], hi, acc[(2*k+1) & 7]);
                }
                f2 s0 = acc[0] + acc[1];
                f2 s1 = acc[2] + acc[3];
                f2 s2 = acc[4] + acc[5];
                f2 s3 = acc[6] + acc[7];
                f2 s  = (s0 + s1) + (s2 + s3);
                const float w = s.x + s.y;

                const float unew = ehq[q] * w * r;
                const bool mm = (m != 0.0f);        // uniform
                u  = mm ? unew : u;
                Ls = mm ? (Ls + __log2f(z)) : Ls;
                __builtin_amdgcn_wave_barrier();
            }
        }
        mreg = mreg_next;
    }

    // out[b] = ln2*Ls + log(sum_i u[i] * exp(trans[EOS, i]))
    float v = u * __expf(trans[EOS_IDX * TAGS + lane]);
    #pragma unroll
    for (int off = 32; off > 0; off >>= 1) v += __shfl_xor(v, off, 64);
    if (lane == 0) out[b] = 0.69314718055994531f * Ls + __logf(v);
}

extern "C" void kernel_launch(void* const* d_in, const int* in_sizes, int n_in,
                              void* d_out, int out_size, void* d_ws, size_t ws_size,
                              hipStream_t stream) {
    const float* h     = (const float*)d_in[0];
    const float* mask  = (const float*)d_in[1];
    const float* trans = (const float*)d_in[2];
    float* out = (float*)d_out;

    const int B = out_size;                 // 512
    const int S = in_sizes[1] / B;          // 1024  (mask is B*S)

    crf_fwd_kernel<<<B, 64, 0, stream>>>(h, mask, trans, out, S);
}

// Round 4
// 330.095 us; speedup vs baseline: 1.4538x; 1.4538x over previous
//
#include <hip/hip_runtime.h>

#define TAGS 64
#define SOS_IDX 1
#define EOS_IDX 2

typedef __attribute__((ext_vector_type(2))) float f2;

// quad_perm DPP: lane <- quad-mate. x1 = swap bit0 [1,0,3,2]; x2 = swap bit1 [2,3,0,1]
#define DPP_X1 0xB1
#define DPP_X2 0x4E
#define DPPF(v, ctrl) \
    __int_as_float(__builtin_amdgcn_mov_dpp(__float_as_int(v), (ctrl), 0xF, 0xF, true))

__device__ __forceinline__ float rl(float v, int l) {
    return __int_as_float(__builtin_amdgcn_readlane(__float_as_int(v), l));
}

// One wave per batch; lane i = 4g+c owns tag i.
// u[i] = exp(score[i]-L); step: u' = exp(h_t) * (E u) / z, Ls += log2(z), z = u_prev[3].
// Split matvec: lane 4g+c reads only u[16c..16c+16) (4x ds_read_b128) and computes
// partials for rows 4g+(c^k), k=0..3; rotated quad reduce-scatter via DPP (no LDS):
//   pp0 += x1(pp1); pp2 += x1(pp3); pp0 += x2(pp2)  ->  w[4g+c] in lane 4g+c.
__global__ __launch_bounds__(64, 1) void crf_fwd_kernel(
    const float* __restrict__ h,
    const float* __restrict__ mask,
    const float* __restrict__ trans,
    float* __restrict__ out,
    int S)
{
    const int b = blockIdx.x;
    const int lane = threadIdx.x;
    const int g = lane >> 2;
    const int c = lane & 3;

    __shared__ __align__(16) float u_sh[TAGS];

    // E fragment: slot k holds exp(trans[4g + (c^k)][16c .. 16c+16)) as 8 f2. 64 VGPRs.
    f2 ew2[4][8];
    #pragma unroll
    for (int k = 0; k < 4; ++k) {
        const int row = 4 * g + (c ^ k);
        const float4* tr = reinterpret_cast<const float4*>(trans + row * TAGS + 16 * c);
        #pragma unroll
        for (int q = 0; q < 4; ++q) {
            float4 v = tr[q];
            f2 lo, hi;
            lo.x = __expf(v.x); lo.y = __expf(v.y);   // exp(-10000) -> 0 exact
            hi.x = __expf(v.z); hi.y = __expf(v.w);
            ew2[k][2*q]   = lo;
            ew2[k][2*q+1] = hi;
        }
    }

    const float* hb = h + (size_t)b * (size_t)S * TAGS + lane;
    const float* mb = mask + (size_t)b * (size_t)S;

    float u  = (lane == SOS_IDX) ? 1.0f : 0.0f;  // exp(score0), score0[SOS]=0
    float Ls = 0.0f;                              // running sum of log2(z)

    // h prefetch, depth 8 (coalesced 256B/wave/step)
    float hbuf[8];
    #pragma unroll
    for (int q = 0; q < 8; ++q) {
        int t = (q < S) ? q : (S - 1);
        hbuf[q] = hb[(size_t)t * TAGS];
    }

    // mask: one coalesced load per 64-step chunk, readlane per step. S%64==0 (S=1024).
    const int NC = S >> 6;
    float mreg = mb[lane];

    const float4* u4 = reinterpret_cast<const float4*>(u_sh);

    for (int ch = 0; ch < NC; ++ch) {
        const int cn = (ch + 1 < NC) ? (ch + 1) : ch;
        float mreg_next = mb[(size_t)cn * 64 + lane];   // used 64 steps from now

        for (int t0 = 0; t0 < 64; t0 += 8) {
            float ehq[8];
            #pragma unroll
            for (int q = 0; q < 8; ++q) ehq[q] = __expf(hbuf[q]);
            const int base = ch * 64 + t0 + 8;
            #pragma unroll
            for (int q = 0; q < 8; ++q) {
                int tn = base + q;
                if (tn > S - 1) tn = S - 1;
                hbuf[q] = hb[(size_t)tn * TAGS];
            }

            #pragma unroll
            for (int q = 0; q < 8; ++q) {
                const float m = rl(mreg, t0 + q);   // uniform
                float z = rl(u, 3);                 // u_prev[3]; finite after t=0
                z = (z > 0.0f) ? z : 1.0f;          // only step 0 has u[3]==0
                const float r = __builtin_amdgcn_rcpf(z);

                u_sh[lane] = u;
                __builtin_amdgcn_wave_barrier();    // single wave: LDS pipe in-order

                float4 cc[4];
                #pragma unroll
                for (int k = 0; k < 4; ++k) cc[k] = u4[(c << 2) + k];

                f2 uu[8];
                #pragma unroll
                for (int k = 0; k < 4; ++k) {
                    f2 lo, hi;
                    lo.x = cc[k].x; lo.y = cc[k].y;
                    hi.x = cc[k].z; hi.y = cc[k].w;
                    uu[2*k]   = lo;
                    uu[2*k+1] = hi;
                }

                float pp[4];
                #pragma unroll
                for (int k = 0; k < 4; ++k) {
                    f2 a = ew2[k][0] * uu[0];
                    f2 bacc = ew2[k][1] * uu[1];
                    a    = __builtin_elementwise_fma(ew2[k][2], uu[2], a);
                    bacc = __builtin_elementwise_fma(ew2[k][3], uu[3], bacc);
                    a    = __builtin_elementwise_fma(ew2[k][4], uu[4], a);
                    bacc = __builtin_elementwise_fma(ew2[k][5], uu[5], bacc);
                    a    = __builtin_elementwise_fma(ew2[k][6], uu[6], a);
                    bacc = __builtin_elementwise_fma(ew2[k][7], uu[7], bacc);
                    a = a + bacc;
                    pp[k] = a.x + a.y;
                }

                // rotated quad reduce-scatter: row 4g+c fully summed into lane 4g+c
                pp[0] += DPPF(pp[1], DPP_X1);
                pp[2] += DPPF(pp[3], DPP_X1);
                pp[0] += DPPF(pp[2], DPP_X2);
                const float w = pp[0];

                const float unew = ehq[q] * w * r;
                const bool mm = (m != 0.0f);        // uniform
                u  = mm ? unew : u;
                Ls = mm ? (Ls + __log2f(z)) : Ls;
                __builtin_amdgcn_wave_barrier();    // reads precede next step's write
            }
        }
        mreg = mreg_next;
    }

    // out[b] = ln2*Ls + log(sum_i u[i] * exp(trans[EOS, i]))
    float v = u * __expf(trans[EOS_IDX * TAGS + lane]);
    #pragma unroll
    for (int off = 32; off > 0; off >>= 1) v += __shfl_xor(v, off, 64);
    if (lane == 0) out[b] = 0.69314718055994531f * Ls + __logf(v);
}

extern "C" void kernel_launch(void* const* d_in, const int* in_sizes, int n_in,
                              void* d_out, int out_size, void* d_ws, size_t ws_size,
                              hipStream_t stream) {
    const float* h     = (const float*)d_in[0];
    const float* mask  = (const float*)d_in[1];
    const float* trans = (const float*)d_in[2];
    float* out = (float*)d_out;

    const int B = out_size;                 // 512
    const int S = in_sizes[1] / B;          // 1024  (mask is B*S)

    crf_fwd_kernel<<<B, 64, 0, stream>>>(h, mask, trans, out, S);
}